// Round 7
// baseline (756.264 us; speedup 1.0000x reference)
//
#include <hip/hip_runtime.h>
#include <hip/hip_bf16.h>

#define SS 2048
#define DDIM 1024

typedef unsigned short u16;
typedef unsigned int u32;
typedef __attribute__((ext_vector_type(8))) short bf16x8_t;
typedef __attribute__((ext_vector_type(4))) float f32x4_t;

__device__ __forceinline__ u16 f2bf(float f) {
  __hip_bfloat16 h = __float2bfloat16(f);
  return *reinterpret_cast<u16*>(&h);
}

__global__ void zero_kernel(u32* zb) { zb[threadIdx.x] = 0u; }

// fused f32 -> bf16 converts for q,k,v. grid (2048, 3), block 256.
__global__ __launch_bounds__(256) void convert3_kernel(
    const float* __restrict__ q, const float* __restrict__ k,
    const float* __restrict__ v, u16* __restrict__ Xq, u16* __restrict__ Xk,
    u16* __restrict__ Xv) {
  const float* src = blockIdx.y == 0 ? q : (blockIdx.y == 1 ? k : v);
  u16* dst = blockIdx.y == 0 ? Xq : (blockIdx.y == 1 ? Xk : Xv);
  int i = blockIdx.x * 256 + threadIdx.x;
  const float4* s = (const float4*)src + (size_t)i * 2;
  float4 f0 = s[0], f1 = s[1];
  u16 o[8] = {f2bf(f0.x), f2bf(f0.y), f2bf(f0.z), f2bf(f0.w),
              f2bf(f1.x), f2bf(f1.y), f2bf(f1.z), f2bf(f1.w)};
  *(uint4*)(dst + (size_t)i * 8) = *(const uint4*)o;
}

// conv3 weights w[o][i][t] f32 -> Wr[o][t*1024+i] bf16. grid (1024,2).
__global__ __launch_bounds__(256) void repack3_kernel(
    const float* __restrict__ wq, const float* __restrict__ wk,
    u16* __restrict__ oq, u16* __restrict__ ok) {
  const float* w = blockIdx.y ? wk : wq;
  u16* out = blockIdx.y ? ok : oq;
  int o = blockIdx.x;
  const float* src = w + (size_t)o * 3072;
  u16* dst = out + (size_t)o * 3072;
  for (int i = threadIdx.x; i < 1024; i += 256) {
    dst[i] = f2bf(src[i * 3 + 0]);
    dst[1024 + i] = f2bf(src[i * 3 + 1]);
    dst[2048 + i] = f2bf(src[i * 3 + 2]);
  }
}

// square [o][k] f32 -> bf16 for wv, wc. grid (1024,2).
__global__ __launch_bounds__(256) void repackc_kernel(
    const float* __restrict__ wv, const float* __restrict__ wc,
    u16* __restrict__ ov, u16* __restrict__ oc) {
  const float* w = blockIdx.y ? wc : wv;
  u16* out = blockIdx.y ? oc : ov;
  size_t i = (size_t)blockIdx.x * 1024 + threadIdx.x * 4;
  float4 f = *(const float4*)(w + i);
  u16 o4[4] = {f2bf(f.x), f2bf(f.y), f2bf(f.z), f2bf(f.w)};
  *(ushort4*)(out + i) = *(const ushort4*)o4;
}

// ---------------------------------------------------------------------------
// FUSED projection GEMM (R7). grid (32, 48): y>>4 = proj (0=Q,1=K,2=V),
// n0 = (y&15)*64, m0 = x*128. 1536 blocks = 6 blocks/CU = 12 waves/CU
// (R6 was 2 blocks/CU -> OccupancyPercent 10.7, MfmaUtil 6.4 = latency-bound).
// Register-staged DOUBLE-BUFFER: loads for k0+32 are issued after the
// post-store barrier and fly while iter k0's ds_read+MFMA execute; the
// vmcnt wait lands at the NEXT iteration's LDS store (after compute) —
// the overlap global_load_lds+syncthreads cannot express.
// Wave microkernel unchanged from R6 (proven): 64x64 = 4x4 mfma 16x16x32.
// ---------------------------------------------------------------------------
__global__ __launch_bounds__(128, 3) void proj_gemm(
    const u16* __restrict__ Xq, const u16* __restrict__ Xk,
    const u16* __restrict__ Xv, const u16* __restrict__ Wq,
    const u16* __restrict__ Wk, const u16* __restrict__ Wv,
    const float* __restrict__ bq, const float* __restrict__ bk,
    const float* __restrict__ bv, u16* __restrict__ Qhb,
    u16* __restrict__ Khb, u16* __restrict__ Vtb,
    const u16* __restrict__ zbuf) {
  __shared__ __attribute__((aligned(16))) u16 As[128][40];
  __shared__ __attribute__((aligned(16))) u16 Bs[64][40];
  const int tid = threadIdx.x;
  const int w = tid >> 6;
  const int ln = tid & 15;
  const int quad = (tid >> 4) & 3;
  const int proj = blockIdx.y >> 4;
  const int n0 = (blockIdx.y & 15) * 64;
  const int m0 = blockIdx.x * 128;
  const u16* Xb = proj == 0 ? Xq : (proj == 1 ? Xk : Xv);
  const u16* Wr = proj == 0 ? Wq : (proj == 1 ? Wk : Wv);
  const float* bias = proj == 0 ? bq : (proj == 1 ? bk : bv);
  const int Kdim = (proj == 2) ? 1024 : 3072;
  const bool conv = (proj != 2);

  uint4 ra[4], rb[2];
  auto loadA = [&](int k0) {
#pragma unroll
    for (int j = 0; j < 4; ++j) {
      int G = tid + 128 * j;
      int row = G >> 2, g = G & 3;
      int gm = m0 + row;
      const u16* src;
      if (conv) {
        int b = gm >> 11, s = gm & 2047;
        int sp = s + (k0 >> 10) - 1;
        src = (sp >= 0 && sp < SS)
                  ? Xb + ((size_t)(b * SS + sp) * 1024 + (k0 & 1023) + g * 8)
                  : zbuf;
      } else {
        src = Xb + ((size_t)gm * 1024 + k0 + g * 8);
      }
      ra[j] = *(const uint4*)src;
    }
  };
  auto loadB = [&](int k0) {
#pragma unroll
    for (int j = 0; j < 2; ++j) {
      int G = tid + 128 * j;
      int row = G >> 2, g = G & 3;
      rb[j] = *(const uint4*)(Wr + (size_t)(n0 + row) * Kdim + k0 + g * 8);
    }
  };

  f32x4_t acc[4][4];
#pragma unroll
  for (int i = 0; i < 4; ++i)
#pragma unroll
    for (int j = 0; j < 4; ++j) acc[i][j] = (f32x4_t){0.f, 0.f, 0.f, 0.f};

  loadA(0);
  loadB(0);
  for (int k0 = 0; k0 < Kdim; k0 += 32) {
    __syncthreads();  // prior iteration's frag reads done
#pragma unroll
    for (int j = 0; j < 4; ++j) {
      int G = tid + 128 * j;
      *(uint4*)&As[G >> 2][(G & 3) * 8] = ra[j];
    }
#pragma unroll
    for (int j = 0; j < 2; ++j) {
      int G = tid + 128 * j;
      *(uint4*)&Bs[G >> 2][(G & 3) * 8] = rb[j];
    }
    __syncthreads();  // LDS visible
    if (k0 + 32 < Kdim) { loadA(k0 + 32); loadB(k0 + 32); }  // prefetch flies

    bf16x8_t a[4], b[4];
#pragma unroll
    for (int mt = 0; mt < 4; ++mt)
      a[mt] = *(const bf16x8_t*)&As[w * 64 + mt * 16 + ln][quad * 8];
#pragma unroll
    for (int nt = 0; nt < 4; ++nt)
      b[nt] = *(const bf16x8_t*)&Bs[nt * 16 + ln][quad * 8];
#pragma unroll
    for (int mt = 0; mt < 4; ++mt)
#pragma unroll
      for (int nt = 0; nt < 4; ++nt)
        acc[mt][nt] = __builtin_amdgcn_mfma_f32_16x16x32_bf16(
            a[mt], b[nt], acc[mt][nt], 0, 0, 0);
  }

  const float scale = (proj == 0) ? 0.125f : 1.0f;
#pragma unroll
  for (int mt = 0; mt < 4; ++mt) {
#pragma unroll
    for (int nt = 0; nt < 4; ++nt) {
      int gn = n0 + nt * 16 + ln;
      float bi = bias[gn];
#pragma unroll
      for (int r = 0; r < 4; ++r) {
        int gm = m0 + w * 64 + mt * 16 + quad * 4 + r;
        float val = (acc[mt][nt][r] + bi) * scale;
        int b = gm >> 11, s = gm & 2047;
        int hh = gn & 15, dd = gn >> 4;  // channel = dd*16 + hh (head FAST)
        if (proj == 2)
          Vtb[((size_t)(b * 16 + hh) * 64 + dd) * SS + s] = f2bf(val);
        else if (proj == 0)
          Qhb[((size_t)(b * 16 + hh) * SS + s) * 64 + dd] = f2bf(val);
        else
          Khb[((size_t)(b * 16 + hh) * SS + s) * 64 + dd] = f2bf(val);
      }
    }
  }
}

// ---------------------------------------------------------------------------
// Final GEMM: d_out[4096][1024] f32 = Aob * Wc^T + bc. Same double-buffered
// staging, 128x64 tile, grid (32,16), block 128.
// ---------------------------------------------------------------------------
__global__ __launch_bounds__(128) void final_gemm(
    const u16* __restrict__ Xb, const u16* __restrict__ Wr,
    const float* __restrict__ bias, float* __restrict__ Cptr) {
  __shared__ __attribute__((aligned(16))) u16 As[128][40];
  __shared__ __attribute__((aligned(16))) u16 Bs[64][40];
  const int tid = threadIdx.x;
  const int w = tid >> 6;
  const int ln = tid & 15;
  const int quad = (tid >> 4) & 3;
  const int m0 = blockIdx.x * 128, n0 = blockIdx.y * 64;

  uint4 ra[4], rb[2];
  auto loadA = [&](int k0) {
#pragma unroll
    for (int j = 0; j < 4; ++j) {
      int G = tid + 128 * j;
      ra[j] = *(const uint4*)(Xb + ((size_t)(m0 + (G >> 2)) * 1024 + k0 + (G & 3) * 8));
    }
  };
  auto loadB = [&](int k0) {
#pragma unroll
    for (int j = 0; j < 2; ++j) {
      int G = tid + 128 * j;
      rb[j] = *(const uint4*)(Wr + (size_t)(n0 + (G >> 2)) * 1024 + k0 + (G & 3) * 8);
    }
  };

  f32x4_t acc[4][4];
#pragma unroll
  for (int i = 0; i < 4; ++i)
#pragma unroll
    for (int j = 0; j < 4; ++j) acc[i][j] = (f32x4_t){0.f, 0.f, 0.f, 0.f};

  loadA(0);
  loadB(0);
  for (int k0 = 0; k0 < 1024; k0 += 32) {
    __syncthreads();
#pragma unroll
    for (int j = 0; j < 4; ++j) {
      int G = tid + 128 * j;
      *(uint4*)&As[G >> 2][(G & 3) * 8] = ra[j];
    }
#pragma unroll
    for (int j = 0; j < 2; ++j) {
      int G = tid + 128 * j;
      *(uint4*)&Bs[G >> 2][(G & 3) * 8] = rb[j];
    }
    __syncthreads();
    if (k0 + 32 < 1024) { loadA(k0 + 32); loadB(k0 + 32); }

    bf16x8_t a[4], b[4];
#pragma unroll
    for (int mt = 0; mt < 4; ++mt)
      a[mt] = *(const bf16x8_t*)&As[w * 64 + mt * 16 + ln][quad * 8];
#pragma unroll
    for (int nt = 0; nt < 4; ++nt)
      b[nt] = *(const bf16x8_t*)&Bs[nt * 16 + ln][quad * 8];
#pragma unroll
    for (int mt = 0; mt < 4; ++mt)
#pragma unroll
      for (int nt = 0; nt < 4; ++nt)
        acc[mt][nt] = __builtin_amdgcn_mfma_f32_16x16x32_bf16(
            a[mt], b[nt], acc[mt][nt], 0, 0, 0);
  }

#pragma unroll
  for (int mt = 0; mt < 4; ++mt) {
#pragma unroll
    for (int nt = 0; nt < 4; ++nt) {
      int gn = n0 + nt * 16 + ln;
      float bi = bias[gn];
#pragma unroll
      for (int r = 0; r < 4; ++r) {
        int gm = m0 + w * 64 + mt * 16 + quad * 4 + r;
        Cptr[(size_t)gm * DDIM + gn] = acc[mt][nt][r] + bi;
      }
    }
  }
}

// ---------------------------------------------------------------------------
// MFMA flash attention, transposed-score (R6, proven) + register-staged
// double-buffer for K/Vt tiles (R7). grid (32, 32), block 256.
// ---------------------------------------------------------------------------
__global__ __launch_bounds__(256, 4) void mfma_attn(
    const u16* __restrict__ Qhb, const u16* __restrict__ Khb,
    const u16* __restrict__ Vtb, u16* __restrict__ Aob) {
  __shared__ __attribute__((aligned(16))) u16 Ks[64][72];
  __shared__ __attribute__((aligned(16))) u16 Vt[64][72];
  __shared__ __attribute__((aligned(16))) u16 Ps[4][16][72];
  const int tid = threadIdx.x;
  const int w = tid >> 6;
  const int ln = tid & 15;
  const int quad = (tid >> 4) & 3;
  const int bh = blockIdx.y;
  const int b = bh >> 4, hh = bh & 15;
  const int s0 = blockIdx.x * 64;

  const u16* qp = Qhb + ((size_t)bh * SS + s0 + w * 16 + ln) * 64 + quad * 8;
  bf16x8_t qf0 = *(const bf16x8_t*)qp;
  bf16x8_t qf1 = *(const bf16x8_t*)(qp + 32);

  uint4 rk[2], rv[2];
  auto loadKV = [&](int kt) {
#pragma unroll
    for (int j = 0; j < 2; ++j) {
      int G = tid + 256 * j;
      int row = G >> 3, g = G & 7;
      rk[j] = *(const uint4*)(Khb + ((size_t)bh * SS + kt * 64 + row) * 64 + g * 8);
      rv[j] = *(const uint4*)(Vtb + ((size_t)bh * 64 + row) * SS + kt * 64 + g * 8);
    }
  };

  float lpart = 0.f;
  f32x4_t oacc[4];
#pragma unroll
  for (int dt = 0; dt < 4; ++dt) oacc[dt] = (f32x4_t){0.f, 0.f, 0.f, 0.f};

  loadKV(0);
  for (int kt = 0; kt < 32; ++kt) {
    __syncthreads();  // prior iteration's K/V frag reads done
#pragma unroll
    for (int j = 0; j < 2; ++j) {
      int G = tid + 256 * j;
      int row = G >> 3, g = G & 7;
      *(uint4*)&Ks[row][g * 8] = rk[j];
      *(uint4*)&Vt[row][g * 8] = rv[j];
    }
    __syncthreads();
    if (kt + 1 < 32) loadKV(kt + 1);  // prefetch flies over compute

    // S^T tiles: sc[kq] = D[kpos=kq*16+quad*4+r][q=ln]
    f32x4_t sc[4];
#pragma unroll
    for (int kq = 0; kq < 4; ++kq) sc[kq] = (f32x4_t){0.f, 0.f, 0.f, 0.f};
#pragma unroll
    for (int kq = 0; kq < 4; ++kq) {
      bf16x8_t kf0 = *(const bf16x8_t*)&Ks[kq * 16 + ln][quad * 8];
      sc[kq] = __builtin_amdgcn_mfma_f32_16x16x32_bf16(kf0, qf0, sc[kq], 0, 0, 0);
      bf16x8_t kf1 = *(const bf16x8_t*)&Ks[kq * 16 + ln][32 + quad * 8];
      sc[kq] = __builtin_amdgcn_mfma_f32_16x16x32_bf16(kf1, qf1, sc[kq], 0, 0, 0);
    }

    // fixed-max softmax: p = exp(min(s,60)), P chunks in A-row layout
#pragma unroll
    for (int kq = 0; kq < 4; ++kq) {
      float p0 = __expf(fminf(sc[kq][0], 60.f));
      float p1 = __expf(fminf(sc[kq][1], 60.f));
      float p2 = __expf(fminf(sc[kq][2], 60.f));
      float p3 = __expf(fminf(sc[kq][3], 60.f));
      lpart += (p0 + p1) + (p2 + p3);
      u32 pk0 = (u32)f2bf(p0) | ((u32)f2bf(p1) << 16);
      u32 pk1 = (u32)f2bf(p2) | ((u32)f2bf(p3) << 16);
      uint2 pk = {pk0, pk1};
      *(uint2*)&Ps[w][ln][kq * 16 + quad * 4] = pk;
    }

    bf16x8_t pa0 = *(const bf16x8_t*)&Ps[w][ln][quad * 8];
    bf16x8_t pa1 = *(const bf16x8_t*)&Ps[w][ln][32 + quad * 8];
#pragma unroll
    for (int dt = 0; dt < 4; ++dt) {
      bf16x8_t v0f = *(const bf16x8_t*)&Vt[dt * 16 + ln][quad * 8];
      oacc[dt] = __builtin_amdgcn_mfma_f32_16x16x32_bf16(pa0, v0f, oacc[dt], 0, 0, 0);
      bf16x8_t v1f = *(const bf16x8_t*)&Vt[dt * 16 + ln][32 + quad * 8];
      oacc[dt] = __builtin_amdgcn_mfma_f32_16x16x32_bf16(pa1, v1f, oacc[dt], 0, 0, 0);
    }
  }

  float lred = lpart;
  lred += __shfl_xor(lred, 16, 64);
  lred += __shfl_xor(lred, 32, 64);
  float inv[4];
#pragma unroll
  for (int r = 0; r < 4; ++r) inv[r] = 1.f / __shfl(lred, quad * 4 + r, 64);

#pragma unroll
  for (int dt = 0; dt < 4; ++dt)
#pragma unroll
    for (int r = 0; r < 4; ++r) {
      int gm = b * SS + s0 + w * 16 + quad * 4 + r;
      Aob[(size_t)gm * DDIM + hh * 64 + dt * 16 + ln] = f2bf(oacc[dt][r] * inv[r]);
    }
}

// ---------------------------------------------------------------------------
// Launch
// ---------------------------------------------------------------------------
extern "C" void kernel_launch(void* const* d_in, const int* in_sizes, int n_in,
                              void* d_out, int out_size, void* d_ws, size_t ws_size,
                              hipStream_t stream) {
  const float* q    = (const float*)d_in[0];
  const float* k    = (const float*)d_in[1];
  const float* v    = (const float*)d_in[2];
  const float* wq_w = (const float*)d_in[3];
  const float* wq_b = (const float*)d_in[4];
  const float* wk_w = (const float*)d_in[5];
  const float* wk_b = (const float*)d_in[6];
  const float* wv_w = (const float*)d_in[7];
  const float* wv_b = (const float*)d_in[8];
  const float* wc_w = (const float*)d_in[9];
  const float* wc_b = (const float*)d_in[10];

  char* ws = (char*)d_ws;
  size_t off = 0;
  u16* zbuf = (u16*)(ws + off); off += 256;
  const size_t SZ_ACT = (size_t)2 * SS * DDIM * 2;  // 8 MB bf16
  u16* Xq  = (u16*)(ws + off); off += SZ_ACT;
  u16* Xk  = (u16*)(ws + off); off += SZ_ACT;
  u16* Xv  = (u16*)(ws + off); off += SZ_ACT;
  u16* Wqr = (u16*)(ws + off); off += (size_t)1024 * 3072 * 2;
  u16* Wkr = (u16*)(ws + off); off += (size_t)1024 * 3072 * 2;
  u16* Wvr = (u16*)(ws + off); off += (size_t)1024 * 1024 * 2;
  u16* Wcr = (u16*)(ws + off); off += (size_t)1024 * 1024 * 2;
  u16* Qhb = (u16*)(ws + off); off += SZ_ACT;
  u16* Khb = (u16*)(ws + off); off += SZ_ACT;
  u16* Vtb = (u16*)(ws + off); off += SZ_ACT;
  u16* Aob = (u16*)(ws + off); off += SZ_ACT;
  if (ws_size < off) return;

  zero_kernel<<<1, 64, 0, stream>>>((u32*)zbuf);
  convert3_kernel<<<dim3(2048, 3), 256, 0, stream>>>(q, k, v, Xq, Xk, Xv);
  repack3_kernel<<<dim3(1024, 2), 256, 0, stream>>>(wq_w, wk_w, Wqr, Wkr);
  repackc_kernel<<<dim3(1024, 2), 256, 0, stream>>>(wv_w, wc_w, Wvr, Wcr);

  proj_gemm<<<dim3(32, 48), 128, 0, stream>>>(
      Xq, Xk, Xv, Wqr, Wkr, Wvr, wq_b, wk_b, wv_b, Qhb, Khb, Vtb, zbuf);

  mfma_attn<<<dim3(32, 32), 256, 0, stream>>>(Qhb, Khb, Vtb, Aob);

  final_gemm<<<dim3(32, 16), 128, 0, stream>>>(Aob, Wcr, wc_b, (float*)d_out);
}

// Round 8
// 731.592 us; speedup vs baseline: 1.0337x; 1.0337x over previous
//
#include <hip/hip_runtime.h>
#include <hip/hip_bf16.h>

#define SS 2048
#define DDIM 1024

typedef unsigned short u16;
typedef unsigned int u32;
typedef __attribute__((ext_vector_type(8))) short bf16x8_t;
typedef __attribute__((ext_vector_type(4))) float f32x4_t;

__device__ __forceinline__ u16 f2bf(float f) {
  __hip_bfloat16 h = __float2bfloat16(f);
  return *reinterpret_cast<u16*>(&h);
}

__global__ void zero_kernel(u32* zb) { zb[threadIdx.x] = 0u; }

// fused f32 -> bf16 converts for q,k,v. grid (2048, 3), block 256.
__global__ __launch_bounds__(256) void convert3_kernel(
    const float* __restrict__ q, const float* __restrict__ k,
    const float* __restrict__ v, u16* __restrict__ Xq, u16* __restrict__ Xk,
    u16* __restrict__ Xv) {
  const float* src = blockIdx.y == 0 ? q : (blockIdx.y == 1 ? k : v);
  u16* dst = blockIdx.y == 0 ? Xq : (blockIdx.y == 1 ? Xk : Xv);
  int i = blockIdx.x * 256 + threadIdx.x;
  const float4* s = (const float4*)src + (size_t)i * 2;
  float4 f0 = s[0], f1 = s[1];
  u16 o[8] = {f2bf(f0.x), f2bf(f0.y), f2bf(f0.z), f2bf(f0.w),
              f2bf(f1.x), f2bf(f1.y), f2bf(f1.z), f2bf(f1.w)};
  *(uint4*)(dst + (size_t)i * 8) = *(const uint4*)o;
}

// Head-major output-channel permute: original channel o = dd*16 + hh
// -> weight row n' = hh*64 + dd, so a 64-wide n-tile is ONE head and the
// GEMM epilogue owns full cache lines (R7 post-mortem: partial-line RMW
// blew WRITE_SIZE to 1.05 GB).
__device__ __forceinline__ int sigma(int o) {
  return ((o & 15) << 6) | (o >> 4);
}

// conv3 weights w[o][i][t] f32 -> Wr[sigma(o)][t*1024+i] bf16. grid (1024,2).
__global__ __launch_bounds__(256) void repack3_kernel(
    const float* __restrict__ wq, const float* __restrict__ wk,
    u16* __restrict__ oq, u16* __restrict__ ok) {
  const float* w = blockIdx.y ? wk : wq;
  u16* out = blockIdx.y ? ok : oq;
  int o = blockIdx.x;
  const float* src = w + (size_t)o * 3072;
  u16* dst = out + (size_t)sigma(o) * 3072;
  for (int i = threadIdx.x; i < 1024; i += 256) {
    dst[i] = f2bf(src[i * 3 + 0]);
    dst[1024 + i] = f2bf(src[i * 3 + 1]);
    dst[2048 + i] = f2bf(src[i * 3 + 2]);
  }
}

// square [o][k] f32 -> bf16. y=0: Wv (head-major permuted rows); y=1: Wc
// (unpermuted — final GEMM's k-dim is already concat order). grid (1024,2).
__global__ __launch_bounds__(256) void repackc_kernel(
    const float* __restrict__ wv, const float* __restrict__ wc,
    u16* __restrict__ ov, u16* __restrict__ oc) {
  int o = blockIdx.x;
  const float* src = (blockIdx.y ? wc : wv) + (size_t)o * 1024;
  u16* dst = (blockIdx.y ? oc + (size_t)o * 1024
                         : ov + (size_t)sigma(o) * 1024);
  for (int i = threadIdx.x * 4; i < 1024; i += 1024) {
    float4 f = *(const float4*)(src + i);
    u16 o4[4] = {f2bf(f.x), f2bf(f.y), f2bf(f.z), f2bf(f.w)};
    *(ushort4*)(dst + i) = *(const ushort4*)o4;
  }
}

// ---------------------------------------------------------------------------
// FUSED projection GEMM. grid (32, 48): y>>4 = proj (0=Q,1=K,2=V),
// head = y&15 (n-tile == one head, head-major weights), m0 = x*128.
// 1536 blocks = 6 blocks/CU. Register-staged double-buffer (R7): next tile's
// global loads fly over this tile's ds_read+MFMA.
// Epilogue (R8): block owns the full [s-range][dd 0..63] slab of its head ->
// every 64B line fully written by one wave; bias via inverse permute.
// ---------------------------------------------------------------------------
__global__ __launch_bounds__(128, 3) void proj_gemm(
    const u16* __restrict__ Xq, const u16* __restrict__ Xk,
    const u16* __restrict__ Xv, const u16* __restrict__ Wq,
    const u16* __restrict__ Wk, const u16* __restrict__ Wv,
    const float* __restrict__ bq, const float* __restrict__ bk,
    const float* __restrict__ bv, u16* __restrict__ Qhb,
    u16* __restrict__ Khb, u16* __restrict__ Vtb,
    const u16* __restrict__ zbuf) {
  __shared__ __attribute__((aligned(16))) u16 As[128][40];
  __shared__ __attribute__((aligned(16))) u16 Bs[64][40];
  const int tid = threadIdx.x;
  const int w = tid >> 6;
  const int ln = tid & 15;
  const int quad = (tid >> 4) & 3;
  const int proj = blockIdx.y >> 4;
  const int n0 = (blockIdx.y & 15) * 64;
  const int m0 = blockIdx.x * 128;
  const u16* Xb = proj == 0 ? Xq : (proj == 1 ? Xk : Xv);
  const u16* Wr = proj == 0 ? Wq : (proj == 1 ? Wk : Wv);
  const float* bias = proj == 0 ? bq : (proj == 1 ? bk : bv);
  const int Kdim = (proj == 2) ? 1024 : 3072;
  const bool conv = (proj != 2);

  uint4 ra[4], rb[2];
  auto loadA = [&](int k0) {
#pragma unroll
    for (int j = 0; j < 4; ++j) {
      int G = tid + 128 * j;
      int row = G >> 2, g = G & 3;
      int gm = m0 + row;
      const u16* src;
      if (conv) {
        int b = gm >> 11, s = gm & 2047;
        int sp = s + (k0 >> 10) - 1;
        src = (sp >= 0 && sp < SS)
                  ? Xb + ((size_t)(b * SS + sp) * 1024 + (k0 & 1023) + g * 8)
                  : zbuf;
      } else {
        src = Xb + ((size_t)gm * 1024 + k0 + g * 8);
      }
      ra[j] = *(const uint4*)src;
    }
  };
  auto loadB = [&](int k0) {
#pragma unroll
    for (int j = 0; j < 2; ++j) {
      int G = tid + 128 * j;
      int row = G >> 2, g = G & 3;
      rb[j] = *(const uint4*)(Wr + (size_t)(n0 + row) * Kdim + k0 + g * 8);
    }
  };

  f32x4_t acc[4][4];
#pragma unroll
  for (int i = 0; i < 4; ++i)
#pragma unroll
    for (int j = 0; j < 4; ++j) acc[i][j] = (f32x4_t){0.f, 0.f, 0.f, 0.f};

  loadA(0);
  loadB(0);
  for (int k0 = 0; k0 < Kdim; k0 += 32) {
    __syncthreads();  // prior iteration's frag reads done
#pragma unroll
    for (int j = 0; j < 4; ++j) {
      int G = tid + 128 * j;
      *(uint4*)&As[G >> 2][(G & 3) * 8] = ra[j];
    }
#pragma unroll
    for (int j = 0; j < 2; ++j) {
      int G = tid + 128 * j;
      *(uint4*)&Bs[G >> 2][(G & 3) * 8] = rb[j];
    }
    __syncthreads();  // LDS visible
    if (k0 + 32 < Kdim) { loadA(k0 + 32); loadB(k0 + 32); }  // prefetch flies

    bf16x8_t a[4], b[4];
#pragma unroll
    for (int mt = 0; mt < 4; ++mt)
      a[mt] = *(const bf16x8_t*)&As[w * 64 + mt * 16 + ln][quad * 8];
#pragma unroll
    for (int nt = 0; nt < 4; ++nt)
      b[nt] = *(const bf16x8_t*)&Bs[nt * 16 + ln][quad * 8];
#pragma unroll
    for (int mt = 0; mt < 4; ++mt)
#pragma unroll
      for (int nt = 0; nt < 4; ++nt)
        acc[mt][nt] = __builtin_amdgcn_mfma_f32_16x16x32_bf16(
            a[mt], b[nt], acc[mt][nt], 0, 0, 0);
  }

  const float scale = (proj == 0) ? 0.125f : 1.0f;
  const int hh = n0 >> 6;  // one head per n-tile
#pragma unroll
  for (int mt = 0; mt < 4; ++mt) {
#pragma unroll
    for (int nt = 0; nt < 4; ++nt) {
      int gn = n0 + nt * 16 + ln;
      int dd = gn & 63;
      float bi = bias[(dd << 4) | hh];  // inverse permute: o = dd*16+hh
#pragma unroll
      for (int r = 0; r < 4; ++r) {
        int gm = m0 + w * 64 + mt * 16 + quad * 4 + r;
        float val = (acc[mt][nt][r] + bi) * scale;
        int b = gm >> 11, s = gm & 2047;
        if (proj == 2)
          Vtb[((size_t)(b * 16 + hh) * 64 + dd) * SS + s] = f2bf(val);
        else if (proj == 0)
          Qhb[((size_t)(b * 16 + hh) * SS + s) * 64 + dd] = f2bf(val);
        else
          Khb[((size_t)(b * 16 + hh) * SS + s) * 64 + dd] = f2bf(val);
      }
    }
  }
}

// ---------------------------------------------------------------------------
// Final GEMM: d_out[4096][1024] f32 = Aob * Wc^T + bc. Double-buffered,
// 128x64 tile, grid (32,16), block 128. f32 stores are lane-contiguous.
// ---------------------------------------------------------------------------
__global__ __launch_bounds__(128) void final_gemm(
    const u16* __restrict__ Xb, const u16* __restrict__ Wr,
    const float* __restrict__ bias, float* __restrict__ Cptr) {
  __shared__ __attribute__((aligned(16))) u16 As[128][40];
  __shared__ __attribute__((aligned(16))) u16 Bs[64][40];
  const int tid = threadIdx.x;
  const int w = tid >> 6;
  const int ln = tid & 15;
  const int quad = (tid >> 4) & 3;
  const int m0 = blockIdx.x * 128, n0 = blockIdx.y * 64;

  uint4 ra[4], rb[2];
  auto loadA = [&](int k0) {
#pragma unroll
    for (int j = 0; j < 4; ++j) {
      int G = tid + 128 * j;
      ra[j] = *(const uint4*)(Xb + ((size_t)(m0 + (G >> 2)) * 1024 + k0 + (G & 3) * 8));
    }
  };
  auto loadB = [&](int k0) {
#pragma unroll
    for (int j = 0; j < 2; ++j) {
      int G = tid + 128 * j;
      rb[j] = *(const uint4*)(Wr + (size_t)(n0 + (G >> 2)) * 1024 + k0 + (G & 3) * 8);
    }
  };

  f32x4_t acc[4][4];
#pragma unroll
  for (int i = 0; i < 4; ++i)
#pragma unroll
    for (int j = 0; j < 4; ++j) acc[i][j] = (f32x4_t){0.f, 0.f, 0.f, 0.f};

  loadA(0);
  loadB(0);
  for (int k0 = 0; k0 < 1024; k0 += 32) {
    __syncthreads();
#pragma unroll
    for (int j = 0; j < 4; ++j) {
      int G = tid + 128 * j;
      *(uint4*)&As[G >> 2][(G & 3) * 8] = ra[j];
    }
#pragma unroll
    for (int j = 0; j < 2; ++j) {
      int G = tid + 128 * j;
      *(uint4*)&Bs[G >> 2][(G & 3) * 8] = rb[j];
    }
    __syncthreads();
    if (k0 + 32 < 1024) { loadA(k0 + 32); loadB(k0 + 32); }

    bf16x8_t a[4], b[4];
#pragma unroll
    for (int mt = 0; mt < 4; ++mt)
      a[mt] = *(const bf16x8_t*)&As[w * 64 + mt * 16 + ln][quad * 8];
#pragma unroll
    for (int nt = 0; nt < 4; ++nt)
      b[nt] = *(const bf16x8_t*)&Bs[nt * 16 + ln][quad * 8];
#pragma unroll
    for (int mt = 0; mt < 4; ++mt)
#pragma unroll
      for (int nt = 0; nt < 4; ++nt)
        acc[mt][nt] = __builtin_amdgcn_mfma_f32_16x16x32_bf16(
            a[mt], b[nt], acc[mt][nt], 0, 0, 0);
  }

#pragma unroll
  for (int mt = 0; mt < 4; ++mt) {
#pragma unroll
    for (int nt = 0; nt < 4; ++nt) {
      int gn = n0 + nt * 16 + ln;
      float bi = bias[gn];
#pragma unroll
      for (int r = 0; r < 4; ++r) {
        int gm = m0 + w * 64 + mt * 16 + quad * 4 + r;
        Cptr[(size_t)gm * DDIM + gn] = acc[mt][nt][r] + bi;
      }
    }
  }
}

// ---------------------------------------------------------------------------
// MFMA flash attention, transposed-score + register-staged double-buffer
// (R6/R7, proven). grid (32, 32), block 256.
// ---------------------------------------------------------------------------
__global__ __launch_bounds__(256, 4) void mfma_attn(
    const u16* __restrict__ Qhb, const u16* __restrict__ Khb,
    const u16* __restrict__ Vtb, u16* __restrict__ Aob) {
  __shared__ __attribute__((aligned(16))) u16 Ks[64][72];
  __shared__ __attribute__((aligned(16))) u16 Vt[64][72];
  __shared__ __attribute__((aligned(16))) u16 Ps[4][16][72];
  const int tid = threadIdx.x;
  const int w = tid >> 6;
  const int ln = tid & 15;
  const int quad = (tid >> 4) & 3;
  const int bh = blockIdx.y;
  const int b = bh >> 4, hh = bh & 15;
  const int s0 = blockIdx.x * 64;

  const u16* qp = Qhb + ((size_t)bh * SS + s0 + w * 16 + ln) * 64 + quad * 8;
  bf16x8_t qf0 = *(const bf16x8_t*)qp;
  bf16x8_t qf1 = *(const bf16x8_t*)(qp + 32);

  uint4 rk[2], rv[2];
  auto loadKV = [&](int kt) {
#pragma unroll
    for (int j = 0; j < 2; ++j) {
      int G = tid + 256 * j;
      int row = G >> 3, g = G & 7;
      rk[j] = *(const uint4*)(Khb + ((size_t)bh * SS + kt * 64 + row) * 64 + g * 8);
      rv[j] = *(const uint4*)(Vtb + ((size_t)bh * 64 + row) * SS + kt * 64 + g * 8);
    }
  };

  float lpart = 0.f;
  f32x4_t oacc[4];
#pragma unroll
  for (int dt = 0; dt < 4; ++dt) oacc[dt] = (f32x4_t){0.f, 0.f, 0.f, 0.f};

  loadKV(0);
  for (int kt = 0; kt < 32; ++kt) {
    __syncthreads();  // prior iteration's K/V frag reads done
#pragma unroll
    for (int j = 0; j < 2; ++j) {
      int G = tid + 256 * j;
      int row = G >> 3, g = G & 7;
      *(uint4*)&Ks[row][g * 8] = rk[j];
      *(uint4*)&Vt[row][g * 8] = rv[j];
    }
    __syncthreads();
    if (kt + 1 < 32) loadKV(kt + 1);  // prefetch flies over compute

    // S^T tiles: sc[kq] = D[kpos=kq*16+quad*4+r][q=ln]
    f32x4_t sc[4];
#pragma unroll
    for (int kq = 0; kq < 4; ++kq) sc[kq] = (f32x4_t){0.f, 0.f, 0.f, 0.f};
#pragma unroll
    for (int kq = 0; kq < 4; ++kq) {
      bf16x8_t kf0 = *(const bf16x8_t*)&Ks[kq * 16 + ln][quad * 8];
      sc[kq] = __builtin_amdgcn_mfma_f32_16x16x32_bf16(kf0, qf0, sc[kq], 0, 0, 0);
      bf16x8_t kf1 = *(const bf16x8_t*)&Ks[kq * 16 + ln][32 + quad * 8];
      sc[kq] = __builtin_amdgcn_mfma_f32_16x16x32_bf16(kf1, qf1, sc[kq], 0, 0, 0);
    }

    // fixed-max softmax: p = exp(min(s,60)), P chunks in A-row layout
#pragma unroll
    for (int kq = 0; kq < 4; ++kq) {
      float p0 = __expf(fminf(sc[kq][0], 60.f));
      float p1 = __expf(fminf(sc[kq][1], 60.f));
      float p2 = __expf(fminf(sc[kq][2], 60.f));
      float p3 = __expf(fminf(sc[kq][3], 60.f));
      lpart += (p0 + p1) + (p2 + p3);
      u32 pk0 = (u32)f2bf(p0) | ((u32)f2bf(p1) << 16);
      u32 pk1 = (u32)f2bf(p2) | ((u32)f2bf(p3) << 16);
      uint2 pk = {pk0, pk1};
      *(uint2*)&Ps[w][ln][kq * 16 + quad * 4] = pk;
    }

    bf16x8_t pa0 = *(const bf16x8_t*)&Ps[w][ln][quad * 8];
    bf16x8_t pa1 = *(const bf16x8_t*)&Ps[w][ln][32 + quad * 8];
#pragma unroll
    for (int dt = 0; dt < 4; ++dt) {
      bf16x8_t v0f = *(const bf16x8_t*)&Vt[dt * 16 + ln][quad * 8];
      oacc[dt] = __builtin_amdgcn_mfma_f32_16x16x32_bf16(pa0, v0f, oacc[dt], 0, 0, 0);
      bf16x8_t v1f = *(const bf16x8_t*)&Vt[dt * 16 + ln][32 + quad * 8];
      oacc[dt] = __builtin_amdgcn_mfma_f32_16x16x32_bf16(pa1, v1f, oacc[dt], 0, 0, 0);
    }
  }

  float lred = lpart;
  lred += __shfl_xor(lred, 16, 64);
  lred += __shfl_xor(lred, 32, 64);
  float inv[4];
#pragma unroll
  for (int r = 0; r < 4; ++r) inv[r] = 1.f / __shfl(lred, quad * 4 + r, 64);

#pragma unroll
  for (int dt = 0; dt < 4; ++dt)
#pragma unroll
    for (int r = 0; r < 4; ++r) {
      int gm = b * SS + s0 + w * 16 + quad * 4 + r;
      Aob[(size_t)gm * DDIM + hh * 64 + dt * 16 + ln] = f2bf(oacc[dt][r] * inv[r]);
    }
}

// ---------------------------------------------------------------------------
// Launch
// ---------------------------------------------------------------------------
extern "C" void kernel_launch(void* const* d_in, const int* in_sizes, int n_in,
                              void* d_out, int out_size, void* d_ws, size_t ws_size,
                              hipStream_t stream) {
  const float* q    = (const float*)d_in[0];
  const float* k    = (const float*)d_in[1];
  const float* v    = (const float*)d_in[2];
  const float* wq_w = (const float*)d_in[3];
  const float* wq_b = (const float*)d_in[4];
  const float* wk_w = (const float*)d_in[5];
  const float* wk_b = (const float*)d_in[6];
  const float* wv_w = (const float*)d_in[7];
  const float* wv_b = (const float*)d_in[8];
  const float* wc_w = (const float*)d_in[9];
  const float* wc_b = (const float*)d_in[10];

  char* ws = (char*)d_ws;
  size_t off = 0;
  u16* zbuf = (u16*)(ws + off); off += 256;
  const size_t SZ_ACT = (size_t)2 * SS * DDIM * 2;  // 8 MB bf16
  u16* Xq  = (u16*)(ws + off); off += SZ_ACT;
  u16* Xk  = (u16*)(ws + off); off += SZ_ACT;
  u16* Xv  = (u16*)(ws + off); off += SZ_ACT;
  u16* Wqr = (u16*)(ws + off); off += (size_t)1024 * 3072 * 2;
  u16* Wkr = (u16*)(ws + off); off += (size_t)1024 * 3072 * 2;
  u16* Wvr = (u16*)(ws + off); off += (size_t)1024 * 1024 * 2;
  u16* Wcr = (u16*)(ws + off); off += (size_t)1024 * 1024 * 2;
  u16* Qhb = (u16*)(ws + off); off += SZ_ACT;
  u16* Khb = (u16*)(ws + off); off += SZ_ACT;
  u16* Vtb = (u16*)(ws + off); off += SZ_ACT;
  u16* Aob = (u16*)(ws + off); off += SZ_ACT;
  if (ws_size < off) return;

  zero_kernel<<<1, 64, 0, stream>>>((u32*)zbuf);
  convert3_kernel<<<dim3(2048, 3), 256, 0, stream>>>(q, k, v, Xq, Xk, Xv);
  repack3_kernel<<<dim3(1024, 2), 256, 0, stream>>>(wq_w, wk_w, Wqr, Wkr);
  repackc_kernel<<<dim3(1024, 2), 256, 0, stream>>>(wv_w, wc_w, Wvr, Wcr);

  proj_gemm<<<dim3(32, 48), 128, 0, stream>>>(
      Xq, Xk, Xv, Wqr, Wkr, Wvr, wq_b, wk_b, wv_b, Qhb, Khb, Vtb, zbuf);

  mfma_attn<<<dim3(32, 32), 256, 0, stream>>>(Qhb, Khb, Vtb, Aob);

  final_gemm<<<dim3(32, 16), 128, 0, stream>>>(Aob, Wcr, wc_b, (float*)d_out);
}

// Round 9
// 727.844 us; speedup vs baseline: 1.0390x; 1.0051x over previous
//
#include <hip/hip_runtime.h>
#include <hip/hip_bf16.h>

#define SS 2048
#define DDIM 1024

typedef unsigned short u16;
typedef unsigned int u32;
typedef __attribute__((ext_vector_type(8))) short bf16x8_t;
typedef __attribute__((ext_vector_type(4))) float f32x4_t;

__device__ __forceinline__ u16 f2bf(float f) {
  __hip_bfloat16 h = __float2bfloat16(f);
  return *reinterpret_cast<u16*>(&h);
}

__global__ void zero_kernel(u32* zb) { zb[threadIdx.x] = 0u; }

// fused f32 -> bf16 converts for q,k,v. grid (2048, 3), block 256.
__global__ __launch_bounds__(256) void convert3_kernel(
    const float* __restrict__ q, const float* __restrict__ k,
    const float* __restrict__ v, u16* __restrict__ Xq, u16* __restrict__ Xk,
    u16* __restrict__ Xv) {
  const float* src = blockIdx.y == 0 ? q : (blockIdx.y == 1 ? k : v);
  u16* dst = blockIdx.y == 0 ? Xq : (blockIdx.y == 1 ? Xk : Xv);
  int i = blockIdx.x * 256 + threadIdx.x;
  const float4* s = (const float4*)src + (size_t)i * 2;
  float4 f0 = s[0], f1 = s[1];
  u16 o[8] = {f2bf(f0.x), f2bf(f0.y), f2bf(f0.z), f2bf(f0.w),
              f2bf(f1.x), f2bf(f1.y), f2bf(f1.z), f2bf(f1.w)};
  *(uint4*)(dst + (size_t)i * 8) = *(const uint4*)o;
}

// Head-major output-channel permute: original channel o = dd*16 + hh
// -> weight row n' = hh*64 + dd (n-tile == one head; epilogue owns full
// cache lines).
__device__ __forceinline__ int sigma(int o) {
  return ((o & 15) << 6) | (o >> 4);
}

// conv3 weights w[o][i][t] f32 -> Wr[sigma(o)][t*1024+i] bf16. grid (1024,2).
__global__ __launch_bounds__(256) void repack3_kernel(
    const float* __restrict__ wq, const float* __restrict__ wk,
    u16* __restrict__ oq, u16* __restrict__ ok) {
  const float* w = blockIdx.y ? wk : wq;
  u16* out = blockIdx.y ? ok : oq;
  int o = blockIdx.x;
  const float* src = w + (size_t)o * 3072;
  u16* dst = out + (size_t)sigma(o) * 3072;
  for (int i = threadIdx.x; i < 1024; i += 256) {
    dst[i] = f2bf(src[i * 3 + 0]);
    dst[1024 + i] = f2bf(src[i * 3 + 1]);
    dst[2048 + i] = f2bf(src[i * 3 + 2]);
  }
}

// square [o][k] f32 -> bf16. y=0: Wv (head-major permuted rows); y=1: Wc
// (unpermuted — final GEMM's k-dim is already concat order). grid (1024,2).
__global__ __launch_bounds__(256) void repackc_kernel(
    const float* __restrict__ wv, const float* __restrict__ wc,
    u16* __restrict__ ov, u16* __restrict__ oc) {
  int o = blockIdx.x;
  const float* src = (blockIdx.y ? wc : wv) + (size_t)o * 1024;
  u16* dst = (blockIdx.y ? oc + (size_t)o * 1024
                         : ov + (size_t)sigma(o) * 1024);
  for (int i = threadIdx.x * 4; i < 1024; i += 1024) {
    float4 f = *(const float4*)(src + i);
    u16 o4[4] = {f2bf(f.x), f2bf(f.y), f2bf(f.z), f2bf(f.w)};
    *(ushort4*)(dst + i) = *(const ushort4*)o4;
  }
}

// ---------------------------------------------------------------------------
// FUSED projection GEMM. grid (32, 48): y>>4 = proj (0=Q,1=K,2=V),
// head = y&15 (n-tile == one head), m0 = x*128. Register-staged
// double-buffer. R9: __launch_bounds__(128) WITHOUT min-waves — the (128,3)
// reg cap squeezed arch VGPRs to 64 and spilled the staged ra/rb tiles to
// scratch: 1.03 GB phantom WRITE_SIZE (R7/R8), kernel 100% scratch-bound.
// ---------------------------------------------------------------------------
__global__ __launch_bounds__(128) void proj_gemm(
    const u16* __restrict__ Xq, const u16* __restrict__ Xk,
    const u16* __restrict__ Xv, const u16* __restrict__ Wq,
    const u16* __restrict__ Wk, const u16* __restrict__ Wv,
    const float* __restrict__ bq, const float* __restrict__ bk,
    const float* __restrict__ bv, u16* __restrict__ Qhb,
    u16* __restrict__ Khb, u16* __restrict__ Vtb,
    const u16* __restrict__ zbuf) {
  __shared__ __attribute__((aligned(16))) u16 As[128][40];
  __shared__ __attribute__((aligned(16))) u16 Bs[64][40];
  const int tid = threadIdx.x;
  const int w = tid >> 6;
  const int ln = tid & 15;
  const int quad = (tid >> 4) & 3;
  const int proj = blockIdx.y >> 4;
  const int n0 = (blockIdx.y & 15) * 64;
  const int m0 = blockIdx.x * 128;
  const u16* Xb = proj == 0 ? Xq : (proj == 1 ? Xk : Xv);
  const u16* Wr = proj == 0 ? Wq : (proj == 1 ? Wk : Wv);
  const float* bias = proj == 0 ? bq : (proj == 1 ? bk : bv);
  const int Kdim = (proj == 2) ? 1024 : 3072;
  const bool conv = (proj != 2);

  uint4 ra[4], rb[2];
  auto loadA = [&](int k0) {
#pragma unroll
    for (int j = 0; j < 4; ++j) {
      int G = tid + 128 * j;
      int row = G >> 2, g = G & 3;
      int gm = m0 + row;
      const u16* src;
      if (conv) {
        int b = gm >> 11, s = gm & 2047;
        int sp = s + (k0 >> 10) - 1;
        src = (sp >= 0 && sp < SS)
                  ? Xb + ((size_t)(b * SS + sp) * 1024 + (k0 & 1023) + g * 8)
                  : zbuf;
      } else {
        src = Xb + ((size_t)gm * 1024 + k0 + g * 8);
      }
      ra[j] = *(const uint4*)src;
    }
  };
  auto loadB = [&](int k0) {
#pragma unroll
    for (int j = 0; j < 2; ++j) {
      int G = tid + 128 * j;
      int row = G >> 2, g = G & 3;
      rb[j] = *(const uint4*)(Wr + (size_t)(n0 + row) * Kdim + k0 + g * 8);
    }
  };

  f32x4_t acc[4][4];
#pragma unroll
  for (int i = 0; i < 4; ++i)
#pragma unroll
    for (int j = 0; j < 4; ++j) acc[i][j] = (f32x4_t){0.f, 0.f, 0.f, 0.f};

  loadA(0);
  loadB(0);
  for (int k0 = 0; k0 < Kdim; k0 += 32) {
    __syncthreads();  // prior iteration's frag reads done
#pragma unroll
    for (int j = 0; j < 4; ++j) {
      int G = tid + 128 * j;
      *(uint4*)&As[G >> 2][(G & 3) * 8] = ra[j];
    }
#pragma unroll
    for (int j = 0; j < 2; ++j) {
      int G = tid + 128 * j;
      *(uint4*)&Bs[G >> 2][(G & 3) * 8] = rb[j];
    }
    __syncthreads();  // LDS visible
    if (k0 + 32 < Kdim) { loadA(k0 + 32); loadB(k0 + 32); }  // prefetch flies

    bf16x8_t a[4], b[4];
#pragma unroll
    for (int mt = 0; mt < 4; ++mt)
      a[mt] = *(const bf16x8_t*)&As[w * 64 + mt * 16 + ln][quad * 8];
#pragma unroll
    for (int nt = 0; nt < 4; ++nt)
      b[nt] = *(const bf16x8_t*)&Bs[nt * 16 + ln][quad * 8];
#pragma unroll
    for (int mt = 0; mt < 4; ++mt)
#pragma unroll
      for (int nt = 0; nt < 4; ++nt)
        acc[mt][nt] = __builtin_amdgcn_mfma_f32_16x16x32_bf16(
            a[mt], b[nt], acc[mt][nt], 0, 0, 0);
  }

  const float scale = (proj == 0) ? 0.125f : 1.0f;
  const int hh = n0 >> 6;  // one head per n-tile
#pragma unroll
  for (int mt = 0; mt < 4; ++mt) {
#pragma unroll
    for (int nt = 0; nt < 4; ++nt) {
      int gn = n0 + nt * 16 + ln;
      int dd = gn & 63;
      float bi = bias[(dd << 4) | hh];  // inverse permute: o = dd*16+hh
#pragma unroll
      for (int r = 0; r < 4; ++r) {
        int gm = m0 + w * 64 + mt * 16 + quad * 4 + r;
        float val = (acc[mt][nt][r] + bi) * scale;
        int b = gm >> 11, s = gm & 2047;
        if (proj == 2)
          Vtb[((size_t)(b * 16 + hh) * 64 + dd) * SS + s] = f2bf(val);
        else if (proj == 0)
          Qhb[((size_t)(b * 16 + hh) * SS + s) * 64 + dd] = f2bf(val);
        else
          Khb[((size_t)(b * 16 + hh) * SS + s) * 64 + dd] = f2bf(val);
      }
    }
  }
}

// ---------------------------------------------------------------------------
// Final GEMM: d_out[4096][1024] f32 = Aob * Wc^T + bc. Double-buffered,
// 128x64 tile, grid (32,16), block 128.
// ---------------------------------------------------------------------------
__global__ __launch_bounds__(128) void final_gemm(
    const u16* __restrict__ Xb, const u16* __restrict__ Wr,
    const float* __restrict__ bias, float* __restrict__ Cptr) {
  __shared__ __attribute__((aligned(16))) u16 As[128][40];
  __shared__ __attribute__((aligned(16))) u16 Bs[64][40];
  const int tid = threadIdx.x;
  const int w = tid >> 6;
  const int ln = tid & 15;
  const int quad = (tid >> 4) & 3;
  const int m0 = blockIdx.x * 128, n0 = blockIdx.y * 64;

  uint4 ra[4], rb[2];
  auto loadA = [&](int k0) {
#pragma unroll
    for (int j = 0; j < 4; ++j) {
      int G = tid + 128 * j;
      ra[j] = *(const uint4*)(Xb + ((size_t)(m0 + (G >> 2)) * 1024 + k0 + (G & 3) * 8));
    }
  };
  auto loadB = [&](int k0) {
#pragma unroll
    for (int j = 0; j < 2; ++j) {
      int G = tid + 128 * j;
      rb[j] = *(const uint4*)(Wr + (size_t)(n0 + (G >> 2)) * 1024 + k0 + (G & 3) * 8);
    }
  };

  f32x4_t acc[4][4];
#pragma unroll
  for (int i = 0; i < 4; ++i)
#pragma unroll
    for (int j = 0; j < 4; ++j) acc[i][j] = (f32x4_t){0.f, 0.f, 0.f, 0.f};

  loadA(0);
  loadB(0);
  for (int k0 = 0; k0 < 1024; k0 += 32) {
    __syncthreads();
#pragma unroll
    for (int j = 0; j < 4; ++j) {
      int G = tid + 128 * j;
      *(uint4*)&As[G >> 2][(G & 3) * 8] = ra[j];
    }
#pragma unroll
    for (int j = 0; j < 2; ++j) {
      int G = tid + 128 * j;
      *(uint4*)&Bs[G >> 2][(G & 3) * 8] = rb[j];
    }
    __syncthreads();
    if (k0 + 32 < 1024) { loadA(k0 + 32); loadB(k0 + 32); }

    bf16x8_t a[4], b[4];
#pragma unroll
    for (int mt = 0; mt < 4; ++mt)
      a[mt] = *(const bf16x8_t*)&As[w * 64 + mt * 16 + ln][quad * 8];
#pragma unroll
    for (int nt = 0; nt < 4; ++nt)
      b[nt] = *(const bf16x8_t*)&Bs[nt * 16 + ln][quad * 8];
#pragma unroll
    for (int mt = 0; mt < 4; ++mt)
#pragma unroll
      for (int nt = 0; nt < 4; ++nt)
        acc[mt][nt] = __builtin_amdgcn_mfma_f32_16x16x32_bf16(
            a[mt], b[nt], acc[mt][nt], 0, 0, 0);
  }

#pragma unroll
  for (int mt = 0; mt < 4; ++mt) {
#pragma unroll
    for (int nt = 0; nt < 4; ++nt) {
      int gn = n0 + nt * 16 + ln;
      float bi = bias[gn];
#pragma unroll
      for (int r = 0; r < 4; ++r) {
        int gm = m0 + w * 64 + mt * 16 + quad * 4 + r;
        Cptr[(size_t)gm * DDIM + gn] = acc[mt][nt][r] + bi;
      }
    }
  }
}

// ---------------------------------------------------------------------------
// MFMA flash attention, transposed-score + register-staged double-buffer.
// R9: plain __launch_bounds__(256) (no min-waves reg cap -> no spill risk).
// grid (32, 32), block 256.
// ---------------------------------------------------------------------------
__global__ __launch_bounds__(256) void mfma_attn(
    const u16* __restrict__ Qhb, const u16* __restrict__ Khb,
    const u16* __restrict__ Vtb, u16* __restrict__ Aob) {
  __shared__ __attribute__((aligned(16))) u16 Ks[64][72];
  __shared__ __attribute__((aligned(16))) u16 Vt[64][72];
  __shared__ __attribute__((aligned(16))) u16 Ps[4][16][72];
  const int tid = threadIdx.x;
  const int w = tid >> 6;
  const int ln = tid & 15;
  const int quad = (tid >> 4) & 3;
  const int bh = blockIdx.y;
  const int b = bh >> 4, hh = bh & 15;
  const int s0 = blockIdx.x * 64;

  const u16* qp = Qhb + ((size_t)bh * SS + s0 + w * 16 + ln) * 64 + quad * 8;
  bf16x8_t qf0 = *(const bf16x8_t*)qp;
  bf16x8_t qf1 = *(const bf16x8_t*)(qp + 32);

  uint4 rk[2], rv[2];
  auto loadKV = [&](int kt) {
#pragma unroll
    for (int j = 0; j < 2; ++j) {
      int G = tid + 256 * j;
      int row = G >> 3, g = G & 7;
      rk[j] = *(const uint4*)(Khb + ((size_t)bh * SS + kt * 64 + row) * 64 + g * 8);
      rv[j] = *(const uint4*)(Vtb + ((size_t)bh * 64 + row) * SS + kt * 64 + g * 8);
    }
  };

  float lpart = 0.f;
  f32x4_t oacc[4];
#pragma unroll
  for (int dt = 0; dt < 4; ++dt) oacc[dt] = (f32x4_t){0.f, 0.f, 0.f, 0.f};

  loadKV(0);
  for (int kt = 0; kt < 32; ++kt) {
    __syncthreads();  // prior iteration's K/V frag reads done
#pragma unroll
    for (int j = 0; j < 2; ++j) {
      int G = tid + 256 * j;
      int row = G >> 3, g = G & 7;
      *(uint4*)&Ks[row][g * 8] = rk[j];
      *(uint4*)&Vt[row][g * 8] = rv[j];
    }
    __syncthreads();
    if (kt + 1 < 32) loadKV(kt + 1);  // prefetch flies over compute

    // S^T tiles: sc[kq] = D[kpos=kq*16+quad*4+r][q=ln]
    f32x4_t sc[4];
#pragma unroll
    for (int kq = 0; kq < 4; ++kq) sc[kq] = (f32x4_t){0.f, 0.f, 0.f, 0.f};
#pragma unroll
    for (int kq = 0; kq < 4; ++kq) {
      bf16x8_t kf0 = *(const bf16x8_t*)&Ks[kq * 16 + ln][quad * 8];
      sc[kq] = __builtin_amdgcn_mfma_f32_16x16x32_bf16(kf0, qf0, sc[kq], 0, 0, 0);
      bf16x8_t kf1 = *(const bf16x8_t*)&Ks[kq * 16 + ln][32 + quad * 8];
      sc[kq] = __builtin_amdgcn_mfma_f32_16x16x32_bf16(kf1, qf1, sc[kq], 0, 0, 0);
    }

    // fixed-max softmax: p = exp(min(s,60)), P chunks in A-row layout
#pragma unroll
    for (int kq = 0; kq < 4; ++kq) {
      float p0 = __expf(fminf(sc[kq][0], 60.f));
      float p1 = __expf(fminf(sc[kq][1], 60.f));
      float p2 = __expf(fminf(sc[kq][2], 60.f));
      float p3 = __expf(fminf(sc[kq][3], 60.f));
      lpart += (p0 + p1) + (p2 + p3);
      u32 pk0 = (u32)f2bf(p0) | ((u32)f2bf(p1) << 16);
      u32 pk1 = (u32)f2bf(p2) | ((u32)f2bf(p3) << 16);
      uint2 pk = {pk0, pk1};
      *(uint2*)&Ps[w][ln][kq * 16 + quad * 4] = pk;
    }

    bf16x8_t pa0 = *(const bf16x8_t*)&Ps[w][ln][quad * 8];
    bf16x8_t pa1 = *(const bf16x8_t*)&Ps[w][ln][32 + quad * 8];
#pragma unroll
    for (int dt = 0; dt < 4; ++dt) {
      bf16x8_t v0f = *(const bf16x8_t*)&Vt[dt * 16 + ln][quad * 8];
      oacc[dt] = __builtin_amdgcn_mfma_f32_16x16x32_bf16(pa0, v0f, oacc[dt], 0, 0, 0);
      bf16x8_t v1f = *(const bf16x8_t*)&Vt[dt * 16 + ln][32 + quad * 8];
      oacc[dt] = __builtin_amdgcn_mfma_f32_16x16x32_bf16(pa1, v1f, oacc[dt], 0, 0, 0);
    }
  }

  float lred = lpart;
  lred += __shfl_xor(lred, 16, 64);
  lred += __shfl_xor(lred, 32, 64);
  float inv[4];
#pragma unroll
  for (int r = 0; r < 4; ++r) inv[r] = 1.f / __shfl(lred, quad * 4 + r, 64);

#pragma unroll
  for (int dt = 0; dt < 4; ++dt)
#pragma unroll
    for (int r = 0; r < 4; ++r) {
      int gm = b * SS + s0 + w * 16 + quad * 4 + r;
      Aob[(size_t)gm * DDIM + hh * 64 + dt * 16 + ln] = f2bf(oacc[dt][r] * inv[r]);
    }
}

// ---------------------------------------------------------------------------
// Launch
// ---------------------------------------------------------------------------
extern "C" void kernel_launch(void* const* d_in, const int* in_sizes, int n_in,
                              void* d_out, int out_size, void* d_ws, size_t ws_size,
                              hipStream_t stream) {
  const float* q    = (const float*)d_in[0];
  const float* k    = (const float*)d_in[1];
  const float* v    = (const float*)d_in[2];
  const float* wq_w = (const float*)d_in[3];
  const float* wq_b = (const float*)d_in[4];
  const float* wk_w = (const float*)d_in[5];
  const float* wk_b = (const float*)d_in[6];
  const float* wv_w = (const float*)d_in[7];
  const float* wv_b = (const float*)d_in[8];
  const float* wc_w = (const float*)d_in[9];
  const float* wc_b = (const float*)d_in[10];

  char* ws = (char*)d_ws;
  size_t off = 0;
  u16* zbuf = (u16*)(ws + off); off += 256;
  const size_t SZ_ACT = (size_t)2 * SS * DDIM * 2;  // 8 MB bf16
  u16* Xq  = (u16*)(ws + off); off += SZ_ACT;
  u16* Xk  = (u16*)(ws + off); off += SZ_ACT;
  u16* Xv  = (u16*)(ws + off); off += SZ_ACT;
  u16* Wqr = (u16*)(ws + off); off += (size_t)1024 * 3072 * 2;
  u16* Wkr = (u16*)(ws + off); off += (size_t)1024 * 3072 * 2;
  u16* Wvr = (u16*)(ws + off); off += (size_t)1024 * 1024 * 2;
  u16* Wcr = (u16*)(ws + off); off += (size_t)1024 * 1024 * 2;
  u16* Qhb = (u16*)(ws + off); off += SZ_ACT;
  u16* Khb = (u16*)(ws + off); off += SZ_ACT;
  u16* Vtb = (u16*)(ws + off); off += SZ_ACT;
  u16* Aob = (u16*)(ws + off); off += SZ_ACT;
  if (ws_size < off) return;

  zero_kernel<<<1, 64, 0, stream>>>((u32*)zbuf);
  convert3_kernel<<<dim3(2048, 3), 256, 0, stream>>>(q, k, v, Xq, Xk, Xv);
  repack3_kernel<<<dim3(1024, 2), 256, 0, stream>>>(wq_w, wk_w, Wqr, Wkr);
  repackc_kernel<<<dim3(1024, 2), 256, 0, stream>>>(wv_w, wc_w, Wvr, Wcr);

  proj_gemm<<<dim3(32, 48), 128, 0, stream>>>(
      Xq, Xk, Xv, Wqr, Wkr, Wvr, wq_b, wk_b, wv_b, Qhb, Khb, Vtb, zbuf);

  mfma_attn<<<dim3(32, 32), 256, 0, stream>>>(Qhb, Khb, Vtb, Aob);

  final_gemm<<<dim3(32, 16), 128, 0, stream>>>(Aob, Wcr, wc_b, (float*)d_out);
}